// Round 7
// baseline (12397.914 us; speedup 1.0000x reference)
//
#include <hip/hip_runtime.h>
#include <hip/hip_bf16.h>
#include <math.h>

// Gated Slot Attention. ROUND 7: ALL-F32 I/O hypothesis.
// Inputs f32, OUTPUT f32 (R4/R5/R6's identical ~1.25 error across disjoint
// implementations + zero-output R3 + NaN R1/R2 are all exactly explained by
// the harness reading d_out as f32 while we wrote bf16).
// Oracle-grade kernels kept from R6 (VALU GEMM, LDS scan); optimize after green.

#define ROWS 8192   // B*T
#define DM 2048

#define MODE_F32 0
#define MODE_SWISH 1
#define MODE_GATE 2

__device__ __forceinline__ float u2f(unsigned short u) {
  union { unsigned int i; float f; } cv; cv.i = ((unsigned int)u) << 16; return cv.f;
}
__device__ __forceinline__ unsigned short f2us(float f) {
  return __builtin_bit_cast(unsigned short, __float2bfloat16(f));
}
__device__ __forceinline__ float swishf(float v) { return v / (1.f + expf(-v)); }

// --------------------------------------------------------------- xnorm ---
// out[row,:] = bf16( in[row,:] * rsqrt(mean(in^2)+eps) * w[:] )
__global__ __launch_bounds__(256) void xnorm_kernel(
    const float* __restrict__ in, const float* __restrict__ w,
    unsigned short* __restrict__ out)
{
  const int row = blockIdx.x, tid = threadIdx.x;
  const size_t base = (size_t)row * DM + tid * 8;
  float a[8];
#pragma unroll
  for (int i = 0; i < 8; ++i) a[i] = in[base + i];
  float ss = 0.f;
#pragma unroll
  for (int i = 0; i < 8; ++i) ss += a[i] * a[i];
#pragma unroll
  for (int off = 32; off; off >>= 1) ss += __shfl_xor(ss, off, 64);
  __shared__ float wsum[4];
  if ((tid & 63) == 0) wsum[tid >> 6] = ss;
  __syncthreads();
  float tot = wsum[0] + wsum[1] + wsum[2] + wsum[3];
  float rstd = rsqrtf(tot * (1.f / (float)DM) + 1e-5f);
#pragma unroll
  for (int i = 0; i < 8; ++i)
    out[base + i] = f2us(a[i] * rstd * w[tid * 8 + i]);
}

// ---------------------------------------------------------- oact_norm ---
// v = swish(o_f32);  out = bf16( v * rsqrt(mean(v^2)+eps) * w )
__global__ __launch_bounds__(256) void oact_norm_kernel(
    const float* __restrict__ o, const float* __restrict__ w,
    unsigned short* __restrict__ out)
{
  const int row = blockIdx.x, tid = threadIdx.x;
  const size_t base = (size_t)row * DM + tid * 8;
  float a[8];
#pragma unroll
  for (int i = 0; i < 8; ++i) a[i] = swishf(o[base + i]);
  float ss = 0.f;
#pragma unroll
  for (int i = 0; i < 8; ++i) ss += a[i] * a[i];
#pragma unroll
  for (int off = 32; off; off >>= 1) ss += __shfl_xor(ss, off, 64);
  __shared__ float wsum[4];
  if ((tid & 63) == 0) wsum[tid >> 6] = ss;
  __syncthreads();
  float tot = wsum[0] + wsum[1] + wsum[2] + wsum[3];
  float rstd = rsqrtf(tot * (1.f / (float)DM) + 1e-5f);
#pragma unroll
  for (int i = 0; i < 8; ++i)
    out[base + i] = f2us(a[i] * rstd * w[tid * 8 + i]);
}

// ---------------------------------------------------------------- GEMM ---
// C[m,n] = epilogue( sum_k A[m,k]*W[n,k] ); A bf16 [8192,2048], W f32 [N,2048]
// MODE_SWISH -> bf16 out; MODE_GATE -> f32 logsigmoid/8; MODE_F32 -> f32 raw.
__global__ __launch_bounds__(256) void vgemm2_kernel(
    const unsigned short* __restrict__ A, const float* __restrict__ W,
    unsigned short* __restrict__ outB, float* __restrict__ outF,
    int N, int mode)
{
  __shared__ __align__(16) float As[32][68];   // [k][m]
  __shared__ __align__(16) float Bs[32][68];   // [k][n]
  const int bn = blockIdx.x, bm = blockIdx.y, tid = threadIdx.x;
  const int r0 = (tid >> 4) * 4, c0 = (tid & 15) * 4;

  float acc[4][4];
#pragma unroll
  for (int i = 0; i < 4; ++i)
#pragma unroll
    for (int j = 0; j < 4; ++j) acc[i][j] = 0.f;

  for (int k0 = 0; k0 < DM; k0 += 32) {
#pragma unroll
    for (int s = 0; s < 2; ++s) {
      int g = tid + s * 256;
      int row = g >> 3;            // 0..63
      int kk = (g & 7) * 4;        // 0..28
      union { uint2 u2; unsigned short us[4]; } t;
      t.u2 = *(const uint2*)(A + (size_t)(bm * 64 + row) * DM + k0 + kk);
      As[kk + 0][row] = u2f(t.us[0]); As[kk + 1][row] = u2f(t.us[1]);
      As[kk + 2][row] = u2f(t.us[2]); As[kk + 3][row] = u2f(t.us[3]);
      float4 bv = *(const float4*)(W + (size_t)(bn * 64 + row) * DM + k0 + kk);
      Bs[kk + 0][row] = bv.x; Bs[kk + 1][row] = bv.y;
      Bs[kk + 2][row] = bv.z; Bs[kk + 3][row] = bv.w;
    }
    __syncthreads();
#pragma unroll
    for (int k = 0; k < 32; ++k) {
      float4 a4 = *(const float4*)&As[k][r0];
      float4 b4 = *(const float4*)&Bs[k][c0];
      float ar[4] = {a4.x, a4.y, a4.z, a4.w};
      float br[4] = {b4.x, b4.y, b4.z, b4.w};
#pragma unroll
      for (int i = 0; i < 4; ++i)
#pragma unroll
        for (int j = 0; j < 4; ++j)
          acc[i][j] = fmaf(ar[i], br[j], acc[i][j]);
    }
    __syncthreads();
  }

#pragma unroll
  for (int i = 0; i < 4; ++i) {
#pragma unroll
    for (int j = 0; j < 4; ++j) {
      int row = bm * 64 + r0 + i;
      int col = bn * 64 + c0 + j;
      float val = acc[i][j];
      size_t idx = (size_t)row * N + col;
      if (mode == MODE_SWISH)      outB[idx] = f2us(swishf(val));
      else if (mode == MODE_F32)   outF[idx] = val;
      else {  // MODE_GATE: log_sigmoid(val)/8
        float ls = fminf(val, 0.f) - log1pf(expf(-fabsf(val)));
        outF[idx] = ls * 0.125f;
      }
    }
  }
}

// ---------------------------------------------------------------- Scan ---
// One block per (b,h), 256 threads. State in LDS:
//   Hk[d][m] (256x64), Hv[m][v] (64x256). O written f32.
__global__ __launch_bounds__(256) void gsa_scan_lds_kernel(
    const unsigned short* __restrict__ Q, const unsigned short* __restrict__ K,
    const unsigned short* __restrict__ V, const float* __restrict__ G,
    float* __restrict__ O)
{
  const int bh = blockIdx.x, b = bh >> 3, h = bh & 7;
  const int tid = threadIdx.x;

  __shared__ float Hk[256][65];
  __shared__ float Hv[64][257];
  __shared__ float q_s[256], k_s[256], v_s[256];
  __shared__ float dec_s[64], s_s[64], qv_s[64], red[4][64];

  for (int idx = tid; idx < 256 * 65; idx += 256) ((float*)Hk)[idx] = 0.f;
  for (int idx = tid; idx < 64 * 257; idx += 256) ((float*)Hv)[idx] = 0.f;
  __syncthreads();

  const int m1 = tid & 63, qa = tid >> 6;

  for (int t = 0; t < 2048; ++t) {
    const size_t rq = (size_t)(b * 2048 + t) * DM + h * 256;
    const size_t rg = (size_t)(b * 2048 + t) * 512 + h * 64;
    q_s[tid] = u2f(Q[rq + tid]);
    k_s[tid] = u2f(K[rq + tid]);
    v_s[tid] = u2f(V[rq + tid]);
    if (tid < 64) {
      float d = expf(fminf(G[rg + tid], 0.f));
      dec_s[tid] = d; s_s[tid] = 1.f - d;
    }
    __syncthreads();

    { // pass 1: Hk[d][m] = Hk*dec[m] + k[d]*s[m];  o1[m] = sum_d q[d]*Hk[d][m]
      float dm = dec_s[m1], sm = s_s[m1];
      float p = 0.f;
      for (int dd = qa * 64; dd < qa * 64 + 64; ++dd) {
        float nh = fmaf(Hk[dd][m1], dm, k_s[dd] * sm);
        Hk[dd][m1] = nh;
        p = fmaf(q_s[dd], nh, p);
      }
      red[qa][m1] = p;
    }
    __syncthreads();

    if (tid < 64) { // softmax over 64 slots
      float o1 = red[0][tid] + red[1][tid] + red[2][tid] + red[3][tid];
      float mx = o1;
#pragma unroll
      for (int off = 32; off; off >>= 1) mx = fmaxf(mx, __shfl_xor(mx, off, 64));
      float e = expf(o1 - mx), se = e;
#pragma unroll
      for (int off = 32; off; off >>= 1) se += __shfl_xor(se, off, 64);
      qv_s[tid] = e / se;
    }
    __syncthreads();

    { // pass 2: Hv[m][v] = Hv*dec[m] + s[m]*v[v];  o[v] = sum_m qv[m]*Hv[m][v]
      float vt = v_s[tid];
      float acc = 0.f;
      for (int m = 0; m < 64; ++m) {
        float nh = fmaf(Hv[m][tid], dec_s[m], s_s[m] * vt);
        Hv[m][tid] = nh;
        acc = fmaf(qv_s[m], nh, acc);
      }
      O[rq + tid] = acc;     // f32
    }
    __syncthreads();
  }
}

// ------------------------------------------------------------- sentinel ---
__global__ __launch_bounds__(256) void fillf_kernel(float* o, float v) {
  o[(size_t)blockIdx.x * 256 + threadIdx.x] = v;
}

// --------------------------------------------------------------- launch ---
extern "C" void kernel_launch(void* const* d_in, const int* in_sizes, int n_in,
                              void* d_out, int out_size, void* d_ws, size_t ws_size,
                              hipStream_t stream)
{
  const float* hidden   = (const float*)d_in[0];
  const float* norm_w   = (const float*)d_in[1];
  const float* q_w      = (const float*)d_in[2];
  const float* k_w      = (const float*)d_in[3];
  const float* v_w      = (const float*)d_in[4];
  const float* f_w      = (const float*)d_in[5];
  const float* g_norm_w = (const float*)d_in[6];
  const float* o_w      = (const float*)d_in[7];

  float* dout = (float*)d_out;                   // f32 output!
  char* ws = (char*)d_ws;
  const size_t SZB = (size_t)ROWS * DM * 2;      // 32MiB bf16 activation
  const size_t SZG = (size_t)ROWS * 512 * 4;     // 16MiB f32 gates
  const size_t NEED = 4 * SZB + SZG;             // 144MiB (proven available in R6)

  if (ws_size < NEED) {
    fillf_kernel<<<65536, 256, 0, stream>>>(dout, 123.0f);
    return;
  }

  unsigned short* XN = (unsigned short*)(ws);      // xnorm, later o_act
  unsigned short* Qb = (unsigned short*)(ws + SZB);
  unsigned short* Kb = (unsigned short*)(ws + 2 * SZB);
  unsigned short* Vb = (unsigned short*)(ws + 3 * SZB);
  float* Gb          = (float*)(ws + 4 * SZB);

  xnorm_kernel<<<ROWS, 256, 0, stream>>>(hidden, norm_w, XN);
  vgemm2_kernel<<<dim3(32, 128), 256, 0, stream>>>(XN, q_w, Qb, nullptr, 2048, MODE_SWISH);
  vgemm2_kernel<<<dim3(32, 128), 256, 0, stream>>>(XN, k_w, Kb, nullptr, 2048, MODE_SWISH);
  vgemm2_kernel<<<dim3(32, 128), 256, 0, stream>>>(XN, v_w, Vb, nullptr, 2048, MODE_SWISH);
  vgemm2_kernel<<<dim3(8, 128), 256, 0, stream>>>(XN, f_w, nullptr, Gb, 512, MODE_GATE);
  gsa_scan_lds_kernel<<<32, 256, 0, stream>>>(Qb, Kb, Vb, Gb, dout);       // o (f32) in d_out
  oact_norm_kernel<<<ROWS, 256, 0, stream>>>(dout, g_norm_w, XN);          // XN = normed swish(o)
  vgemm2_kernel<<<dim3(32, 128), 256, 0, stream>>>(XN, o_w, nullptr, dout, 2048, MODE_F32);
}

// Round 8
// 4755.824 us; speedup vs baseline: 2.6069x; 2.6069x over previous
//
#include <hip/hip_runtime.h>
#include <hip/hip_bf16.h>
#include <math.h>

// Gated Slot Attention. Inputs f32, output f32 (validated R7).
// ROUND 8: MFMA GEMMs (R4-validated layouts) + register-state scan
// (R4-validated structure) with next-step prefetch.

typedef __bf16 bf16x8 __attribute__((ext_vector_type(8)));
typedef float f32x4 __attribute__((ext_vector_type(4)));

#define ROWS 8192   // B*T
#define DM 2048

#define MODE_F32 0
#define MODE_SWISH 1
#define MODE_GATE 2

__device__ __forceinline__ float u2f(unsigned short u) {
  union { unsigned int i; float f; } cv; cv.i = ((unsigned int)u) << 16; return cv.f;
}
__device__ __forceinline__ unsigned short f2us(float f) {
  return __builtin_bit_cast(unsigned short, __float2bfloat16(f));
}
__device__ __forceinline__ float swishf(float v) { return v / (1.f + expf(-v)); }

// --------------------------------------------------------------- xnorm ---
__global__ __launch_bounds__(256) void xnorm_kernel(
    const float* __restrict__ in, const float* __restrict__ w,
    unsigned short* __restrict__ out)
{
  const int row = blockIdx.x, tid = threadIdx.x;
  const size_t base = (size_t)row * DM + tid * 8;
  float a[8];
#pragma unroll
  for (int i = 0; i < 8; ++i) a[i] = in[base + i];
  float ss = 0.f;
#pragma unroll
  for (int i = 0; i < 8; ++i) ss += a[i] * a[i];
#pragma unroll
  for (int off = 32; off; off >>= 1) ss += __shfl_xor(ss, off, 64);
  __shared__ float wsum[4];
  if ((tid & 63) == 0) wsum[tid >> 6] = ss;
  __syncthreads();
  float tot = wsum[0] + wsum[1] + wsum[2] + wsum[3];
  float rstd = rsqrtf(tot * (1.f / (float)DM) + 1e-5f);
#pragma unroll
  for (int i = 0; i < 8; ++i)
    out[base + i] = f2us(a[i] * rstd * w[tid * 8 + i]);
}

// ---------------------------------------------------------- oact_norm ---
__global__ __launch_bounds__(256) void oact_norm_kernel(
    const float* __restrict__ o, const float* __restrict__ w,
    unsigned short* __restrict__ out)
{
  const int row = blockIdx.x, tid = threadIdx.x;
  const size_t base = (size_t)row * DM + tid * 8;
  float a[8];
#pragma unroll
  for (int i = 0; i < 8; ++i) a[i] = swishf(o[base + i]);
  float ss = 0.f;
#pragma unroll
  for (int i = 0; i < 8; ++i) ss += a[i] * a[i];
#pragma unroll
  for (int off = 32; off; off >>= 1) ss += __shfl_xor(ss, off, 64);
  __shared__ float wsum[4];
  if ((tid & 63) == 0) wsum[tid >> 6] = ss;
  __syncthreads();
  float tot = wsum[0] + wsum[1] + wsum[2] + wsum[3];
  float rstd = rsqrtf(tot * (1.f / (float)DM) + 1e-5f);
#pragma unroll
  for (int i = 0; i < 8; ++i)
    out[base + i] = f2us(a[i] * rstd * w[tid * 8 + i]);
}

// ------------------------------------------------------------ MFMA GEMM ---
// C[m,n] = epilogue( sum_k A[m,k]*W[n,k] ); A bf16 [8192,2048], W f32 [N,2048]
// 128x128 tile, BK=32, 2x2 waves of 64x64, mfma 16x16x32 bf16 (R4-validated).
#define BM 128
#define BN 128
#define BK 32
#define LDSP 40

__global__ __launch_bounds__(256) void mgemm_kernel(
    const unsigned short* __restrict__ A, const float* __restrict__ W,
    unsigned short* __restrict__ outB, float* __restrict__ outF,
    int N, int mode)
{
  __shared__ __align__(16) unsigned short As[BM][LDSP];
  __shared__ __align__(16) unsigned short Bs[BN][LDSP];
  const int bn = blockIdx.x, bm = blockIdx.y, tid = threadIdx.x;
  const int w = tid >> 6, l = tid & 63;
  const int wm = w & 1, wn = w >> 1;
  const int fr = l & 15, fq = l >> 4;

  f32x4 acc[4][4];
#pragma unroll
  for (int i = 0; i < 4; ++i)
#pragma unroll
    for (int j = 0; j < 4; ++j) acc[i][j] = (f32x4){0.f, 0.f, 0.f, 0.f};

  for (int k0 = 0; k0 < DM; k0 += BK) {
    // A staging: 128x32 bf16 = 512 uint4 chunks (8 bf16 each)
#pragma unroll
    for (int s = 0; s < 2; ++s) {
      int chunk = tid + s * 256;
      int row = chunk >> 2;
      int cc = (chunk & 3) * 8;
      *(uint4*)&As[row][cc] =
          *(const uint4*)(A + (size_t)(bm * BM + row) * DM + k0 + cc);
    }
    // W staging: 128x32 f32 -> bf16, 1024 float4 chunks
#pragma unroll
    for (int s = 0; s < 4; ++s) {
      int chunk = tid + s * 256;
      int row = chunk >> 3;
      int cc = (chunk & 7) * 4;
      float4 wv = *(const float4*)(W + (size_t)(bn * BN + row) * DM + k0 + cc);
      ushort4 w4;
      w4.x = f2us(wv.x); w4.y = f2us(wv.y); w4.z = f2us(wv.z); w4.w = f2us(wv.w);
      *(ushort4*)&Bs[row][cc] = w4;
    }
    __syncthreads();
    bf16x8 af[4], bfr[4];
#pragma unroll
    for (int i = 0; i < 4; ++i) af[i] = *(const bf16x8*)&As[wm * 64 + i * 16 + fr][fq * 8];
#pragma unroll
    for (int j = 0; j < 4; ++j) bfr[j] = *(const bf16x8*)&Bs[wn * 64 + j * 16 + fr][fq * 8];
#pragma unroll
    for (int i = 0; i < 4; ++i)
#pragma unroll
      for (int j = 0; j < 4; ++j)
        acc[i][j] = __builtin_amdgcn_mfma_f32_16x16x32_bf16(af[i], bfr[j], acc[i][j], 0, 0, 0);
    __syncthreads();
  }

  // D layout (R4/R5-validated): row=(lane>>4)*4+reg, col=lane&15
#pragma unroll
  for (int i = 0; i < 4; ++i) {
#pragma unroll
    for (int rr = 0; rr < 4; ++rr) {
      int row = bm * BM + wm * 64 + i * 16 + fq * 4 + rr;
#pragma unroll
      for (int j = 0; j < 4; ++j) {
        int col = bn * BN + wn * 64 + j * 16 + fr;
        float val = acc[i][j][rr];
        size_t idx = (size_t)row * N + col;
        if (mode == MODE_SWISH)      outB[idx] = f2us(swishf(val));
        else if (mode == MODE_F32)   outF[idx] = val;
        else {  // MODE_GATE
          float ls = fminf(val, 0.f) - log1pf(expf(-fabsf(val)));
          outF[idx] = ls * 0.125f;
        }
      }
    }
  }
}

// ---------------------------------------------------------------- Scan ---
// One block per (b,h), 1024 threads, register-resident state (R4-validated):
//  pass1: thread (m1=tid&63, dc=tid>>6) owns Hk[dc*16+j][m1], j=0..15
//  pass2: thread (vv=tid&255, mc=tid>>8) owns Hv[mc*16+j][vv], j=0..15
// Next-step q/k/v/g prefetched into registers during compute.
__global__ __launch_bounds__(1024) void gsa_scan_reg_kernel(
    const unsigned short* __restrict__ Q, const unsigned short* __restrict__ K,
    const unsigned short* __restrict__ V, const float* __restrict__ G,
    float* __restrict__ O)
{
  const int bh = blockIdx.x, b = bh >> 3, h = bh & 7;
  const int tid = threadIdx.x;

  __shared__ float q_s[256], k_s[256], v_s[256];
  __shared__ float dec_s[64], s_s[64], qv_s[64];
  __shared__ float red1[16][64];
  __shared__ float red2[4][256];

  const int m1 = tid & 63, dc = tid >> 6;
  const int vv = tid & 255, mc = tid >> 8;

  float hk[16], hv[16];
#pragma unroll
  for (int j = 0; j < 16; ++j) { hk[j] = 0.f; hv[j] = 0.f; }

  const size_t base_qkv = (size_t)b * 2048 * DM + h * 256;
  const size_t base_g   = (size_t)b * 2048 * 512 + h * 64;

  // prefetch t=0
  float pre = 0.f;
  {
    if (tid < 256)      pre = u2f(Q[base_qkv + tid]);
    else if (tid < 512) pre = u2f(K[base_qkv + tid - 256]);
    else if (tid < 768) pre = u2f(V[base_qkv + tid - 512]);
    else if (tid < 832) pre = G[base_g + tid - 768];
  }

  for (int t = 0; t < 2048; ++t) {
    // stage step t from registers
    if (tid < 256)      q_s[tid] = pre;
    else if (tid < 512) k_s[tid - 256] = pre;
    else if (tid < 768) v_s[tid - 512] = pre;
    else if (tid < 832) {
      int i = tid - 768;
      float d = expf(fminf(pre, 0.f));
      dec_s[i] = d; s_s[i] = 1.f - d;
    }
    __syncthreads();                                   // (1)

    // prefetch t+1 (overlaps with compute below)
    float nxt = 0.f;
    if (t + 1 < 2048) {
      const size_t rq = base_qkv + (size_t)(t + 1) * DM;
      const size_t rg = base_g + (size_t)(t + 1) * 512;
      if (tid < 256)      nxt = u2f(Q[rq + tid]);
      else if (tid < 512) nxt = u2f(K[rq + tid - 256]);
      else if (tid < 768) nxt = u2f(V[rq + tid - 512]);
      else if (tid < 832) nxt = G[rg + tid - 768];
    }

    { // pass 1: Hk update + o1 partials
      float sm = s_s[m1], dm = dec_s[m1];
      float p = 0.f;
#pragma unroll
      for (int j = 0; j < 16; ++j) {
        int d_ = (dc << 4) + j;
        float hkv = fmaf(hk[j], dm, k_s[d_] * sm);
        hk[j] = hkv;
        p = fmaf(q_s[d_], hkv, p);
      }
      red1[dc][m1] = p;
    }
    __syncthreads();                                   // (2)

    if (tid < 64) { // softmax over 64 slots
      float o1 = 0.f;
#pragma unroll
      for (int c = 0; c < 16; ++c) o1 += red1[c][tid];
      float mx = o1;
#pragma unroll
      for (int off = 32; off; off >>= 1) mx = fmaxf(mx, __shfl_xor(mx, off, 64));
      float e = expf(o1 - mx), se = e;
#pragma unroll
      for (int off = 32; off; off >>= 1) se += __shfl_xor(se, off, 64);
      qv_s[tid] = e / se;
    }
    __syncthreads();                                   // (3)

    { // pass 2: Hv update + output partials
      float vt = v_s[vv];
      float po = 0.f;
#pragma unroll
      for (int j = 0; j < 16; ++j) {
        int mm = (mc << 4) + j;
        float hvv = fmaf(hv[j], dec_s[mm], s_s[mm] * vt);
        hv[j] = hvv;
        po = fmaf(qv_s[mm], hvv, po);
      }
      red2[mc][vv] = po;
    }
    __syncthreads();                                   // (4)

    if (tid < 256)
      O[base_qkv + (size_t)t * DM + tid] =
          red2[0][tid] + red2[1][tid] + red2[2][tid] + red2[3][tid];
    pre = nxt;
    // next iteration's LDS stores are safe: pass2 LDS reads completed at (4);
    // red2 is not rewritten until after next (3).
  }
}

// ------------------------------------------------------------- sentinel ---
__global__ __launch_bounds__(256) void fillf_kernel(float* o, float v) {
  o[(size_t)blockIdx.x * 256 + threadIdx.x] = v;
}

// --------------------------------------------------------------- launch ---
extern "C" void kernel_launch(void* const* d_in, const int* in_sizes, int n_in,
                              void* d_out, int out_size, void* d_ws, size_t ws_size,
                              hipStream_t stream)
{
  const float* hidden   = (const float*)d_in[0];
  const float* norm_w   = (const float*)d_in[1];
  const float* q_w      = (const float*)d_in[2];
  const float* k_w      = (const float*)d_in[3];
  const float* v_w      = (const float*)d_in[4];
  const float* f_w      = (const float*)d_in[5];
  const float* g_norm_w = (const float*)d_in[6];
  const float* o_w      = (const float*)d_in[7];

  float* dout = (float*)d_out;
  char* ws = (char*)d_ws;
  const size_t SZB = (size_t)ROWS * DM * 2;      // 32MiB bf16 activation
  const size_t SZG = (size_t)ROWS * 512 * 4;     // 16MiB f32 gates
  const size_t NEED = 4 * SZB + SZG;             // 144MiB (available per R6/R7)

  if (ws_size < NEED) {
    fillf_kernel<<<65536, 256, 0, stream>>>(dout, 123.0f);
    return;
  }

  unsigned short* XN = (unsigned short*)(ws);      // xnorm, later o_act
  unsigned short* Qb = (unsigned short*)(ws + SZB);
  unsigned short* Kb = (unsigned short*)(ws + 2 * SZB);
  unsigned short* Vb = (unsigned short*)(ws + 3 * SZB);
  float* Gb          = (float*)(ws + 4 * SZB);

  xnorm_kernel<<<ROWS, 256, 0, stream>>>(hidden, norm_w, XN);
  mgemm_kernel<<<dim3(16, 64), 256, 0, stream>>>(XN, q_w, Qb, nullptr, 2048, MODE_SWISH);
  mgemm_kernel<<<dim3(16, 64), 256, 0, stream>>>(XN, k_w, Kb, nullptr, 2048, MODE_SWISH);
  mgemm_kernel<<<dim3(16, 64), 256, 0, stream>>>(XN, v_w, Vb, nullptr, 2048, MODE_SWISH);
  mgemm_kernel<<<dim3(4, 64), 256, 0, stream>>>(XN, f_w, nullptr, Gb, 512, MODE_GATE);
  gsa_scan_reg_kernel<<<32, 1024, 0, stream>>>(Qb, Kb, Vb, Gb, dout);
  oact_norm_kernel<<<ROWS, 256, 0, stream>>>(dout, g_norm_w, XN);
  mgemm_kernel<<<dim3(16, 64), 256, 0, stream>>>(XN, o_w, nullptr, dout, 2048, MODE_F32);
}